// Round 7
// baseline (497.035 us; speedup 1.0000x reference)
//
#include <hip/hip_runtime.h>
#include <cstdint>
#include <math.h>

#define B_ 4
#define S_ 2048
#define D_ 512
#define H_ 8
#define DK_ 64
#define SCALE 0.125f
#define INVLN2 1.4426950408889634f
#define QSCALE (SCALE * INVLN2)   // folded into Q at projection time
#define KSTR 84   // K/V LDS row stride in bf16 (measured conflict-free)
#define PSTR 68   // Ps LDS row stride in bf16 (measured conflict-free)

using bfrag = __attribute__((ext_vector_type(8))) __bf16;
using b4    = __attribute__((ext_vector_type(4))) __bf16;
using f4    = __attribute__((ext_vector_type(4))) float;
using f2    = __attribute__((ext_vector_type(2))) float;
using f16v  = __attribute__((ext_vector_type(16))) float;
using u2    = __attribute__((ext_vector_type(2))) unsigned int;

#define MFMA16(a, b, c) __builtin_amdgcn_mfma_f32_16x16x32_bf16(a, b, c, 0, 0, 0)
#define MFMA32(a, b, c) __builtin_amdgcn_mfma_f32_32x32x16_bf16(a, b, c, 0, 0, 0)

// ---------------------------------------------------------------------------
// All 4 weight transposes in one launch: grid (1024, 4).
// ---------------------------------------------------------------------------
__global__ __launch_bounds__(256) void wtr_all(
    const float* __restrict__ Wqkv, const float* __restrict__ Wout,
    __bf16* __restrict__ WqTh, __bf16* __restrict__ WqTl,
    __bf16* __restrict__ WkTh, __bf16* __restrict__ WkTl,
    __bf16* __restrict__ WvTh, __bf16* __restrict__ WoTh) {
  const int by = blockIdx.y;
  const int idx = blockIdx.x * 256 + threadIdx.x;  // 512*512
  const int k = idx & 511, n = idx >> 9;
  const float* W = (by == 3) ? Wout : Wqkv;
  const int ldw = (by == 3) ? 512 : 1536;
  const int c0 = (by == 3) ? 0 : by * 512;
  const float x = W[(size_t)k * ldw + c0 + n];
  const __bf16 h = (__bf16)x;
  __bf16* th = (by == 0) ? WqTh : (by == 1) ? WkTh : (by == 2) ? WvTh : WoTh;
  th[(size_t)n * 512 + k] = h;
  if (by < 2) {
    __bf16* tl = (by == 0) ? WqTl : WkTl;
    tl[(size_t)n * 512 + k] = (__bf16)(x - (float)h);
  }
}

// ---------------------------------------------------------------------------
// Merged Q+K projection: grid (8, 128, 2); z=0 -> Q (scaled by SCALE/ln2 for
// the exp2-domain softmax), z=1 -> K. Body = verified AF32/LO/MODE1 path.
// ---------------------------------------------------------------------------
__global__ __launch_bounds__(256) void qk_proj(
    const float* __restrict__ Zq, const float* __restrict__ Zkv,
    const __bf16* __restrict__ WqTh, const __bf16* __restrict__ WqTl,
    const __bf16* __restrict__ WkTh, const __bf16* __restrict__ WkTl,
    __bf16* __restrict__ Qh, __bf16* __restrict__ Ql,
    __bf16* __restrict__ Kh, __bf16* __restrict__ Kl) {
  __shared__ __bf16 Ash[64 * 40];
  __shared__ __bf16 Asl[64 * 40];
  __shared__ __bf16 Bsh[64 * 40];
  __shared__ __bf16 Bsl[64 * 40];

  const int zz = blockIdx.z;
  const float* A = zz ? Zkv : Zq;
  const __bf16* Bhp = zz ? WkTh : WqTh;
  const __bf16* Blp = zz ? WkTl : WqTl;
  __bf16* Oh = zz ? Kh : Qh;
  __bf16* Ol = zz ? Kl : Ql;
  const float cs = zz ? 1.0f : QSCALE;

  const int tid = threadIdx.x;
  const int m0 = blockIdx.y * 64, n0 = blockIdx.x * 64;
  const int row = tid >> 2, seg = tid & 3;
  const int lane = tid & 63, wv = tid >> 6;
  const int wm = (wv & 1) * 32, wn = (wv >> 1) * 32;
  const int qd = lane >> 4, ln = lane & 15;

  f4 acc[2][2];
#pragma unroll
  for (int i = 0; i < 2; i++)
#pragma unroll
    for (int j = 0; j < 2; j++)
#pragma unroll
      for (int r = 0; r < 4; r++) acc[i][j][r] = 0.f;

  for (int kt = 0; kt < 512; kt += 32) {
    const size_t abase = (size_t)(m0 + row) * 512 + kt + seg * 8;
    const size_t bbase = (size_t)(n0 + row) * 512 + kt + seg * 8;
    float4 a0 = *(const float4*)&A[abase];
    float4 a1 = *(const float4*)&A[abase + 4];
    float4 b0 = *(const float4*)&Bhp[bbase];
    float4 bl0 = *(const float4*)&Blp[bbase];
    __syncthreads();
    {
      float x[8] = {a0.x, a0.y, a0.z, a0.w, a1.x, a1.y, a1.z, a1.w};
      bfrag h, l;
#pragma unroll
      for (int j = 0; j < 8; j++) {
        h[j] = (__bf16)x[j];
        l[j] = (__bf16)(x[j] - (float)h[j]);
      }
      *(bfrag*)&Ash[row * 40 + seg * 8] = h;
      *(bfrag*)&Asl[row * 40 + seg * 8] = l;
    }
    *(float4*)&Bsh[row * 40 + seg * 8] = b0;
    *(float4*)&Bsl[row * 40 + seg * 8] = bl0;
    __syncthreads();

    bfrag ah[2], al[2], bh[2], bl[2];
#pragma unroll
    for (int mi = 0; mi < 2; mi++) {
      ah[mi] = *(bfrag*)&Ash[(wm + mi * 16 + ln) * 40 + qd * 8];
      al[mi] = *(bfrag*)&Asl[(wm + mi * 16 + ln) * 40 + qd * 8];
    }
#pragma unroll
    for (int ni = 0; ni < 2; ni++) {
      bh[ni] = *(bfrag*)&Bsh[(wn + ni * 16 + ln) * 40 + qd * 8];
      bl[ni] = *(bfrag*)&Bsl[(wn + ni * 16 + ln) * 40 + qd * 8];
    }
#pragma unroll
    for (int mi = 0; mi < 2; mi++)
#pragma unroll
      for (int ni = 0; ni < 2; ni++) {
        acc[mi][ni] = MFMA16(ah[mi], bh[ni], acc[mi][ni]);
        acc[mi][ni] = MFMA16(ah[mi], bl[ni], acc[mi][ni]);
        acc[mi][ni] = MFMA16(al[mi], bh[ni], acc[mi][ni]);
      }
  }

#pragma unroll
  for (int mi = 0; mi < 2; mi++)
#pragma unroll
    for (int ni = 0; ni < 2; ni++)
#pragma unroll
      for (int r = 0; r < 4; r++) {
        const int mrow = m0 + wm + mi * 16 + qd * 4 + r;
        const int ncol = n0 + wn + ni * 16 + ln;
        const float c = acc[mi][ni][r] * cs;
        const int b = mrow >> 11, s = mrow & (S_ - 1);
        const int h = ncol >> 6, dk = ncol & 63;
        const size_t o = (((size_t)b * H_ + h) * S_ + s) * DK_ + dk;
        __bf16 hh = (__bf16)c;
        Oh[o] = hh;
        Ol[o] = (__bf16)(c - (float)hh);
      }
}

// ---------------------------------------------------------------------------
// Split-bf16 MFMA GEMM (template kept for V^T MODE2 and out MODE0).
// ---------------------------------------------------------------------------
template <bool AF32, bool BF32, bool LO, int MODE>
__global__ __launch_bounds__(256) void gemm_mfma(
    const void* __restrict__ Ap, const void* __restrict__ Bp, const void* __restrict__ Blop,
    float* __restrict__ Cf, __bf16* __restrict__ Oh, __bf16* __restrict__ Ol) {
  __shared__ __bf16 Ash[64 * 40];
  __shared__ __bf16 Asl[64 * 40];
  __shared__ __bf16 Bsh[64 * 40];
  __shared__ __bf16 Bsl[64 * 40];

  const int tid = threadIdx.x;
  const int m0 = blockIdx.y * 64, n0 = blockIdx.x * 64;
  const int row = tid >> 2, seg = tid & 3;
  const int lane = tid & 63, wv = tid >> 6;
  const int wm = (wv & 1) * 32, wn = (wv >> 1) * 32;
  const int qd = lane >> 4, ln = lane & 15;

  f4 acc[2][2];
#pragma unroll
  for (int i = 0; i < 2; i++)
#pragma unroll
    for (int j = 0; j < 2; j++)
#pragma unroll
      for (int r = 0; r < 4; r++) acc[i][j][r] = 0.f;

  for (int kt = 0; kt < 512; kt += 32) {
    const size_t abase = (size_t)(m0 + row) * 512 + kt + seg * 8;
    const size_t bbase = (size_t)(n0 + row) * 512 + kt + seg * 8;
    float4 a0, a1, b0, b1, bl0;
    if constexpr (AF32) {
      const float* A = (const float*)Ap;
      a0 = *(const float4*)&A[abase];
      a1 = *(const float4*)&A[abase + 4];
    } else {
      const __bf16* A = (const __bf16*)Ap;
      a0 = *(const float4*)&A[abase];
    }
    if constexpr (BF32) {
      const float* Bm = (const float*)Bp;
      b0 = *(const float4*)&Bm[bbase];
      b1 = *(const float4*)&Bm[bbase + 4];
    } else {
      const __bf16* Bm = (const __bf16*)Bp;
      b0 = *(const float4*)&Bm[bbase];
      if constexpr (LO) {
        const __bf16* Bl = (const __bf16*)Blop;
        bl0 = *(const float4*)&Bl[bbase];
      }
    }
    __syncthreads();
    if constexpr (AF32) {
      float x[8] = {a0.x, a0.y, a0.z, a0.w, a1.x, a1.y, a1.z, a1.w};
      bfrag h, l;
#pragma unroll
      for (int j = 0; j < 8; j++) {
        h[j] = (__bf16)x[j];
        l[j] = (__bf16)(x[j] - (float)h[j]);
      }
      *(bfrag*)&Ash[row * 40 + seg * 8] = h;
      if constexpr (LO) *(bfrag*)&Asl[row * 40 + seg * 8] = l;
    } else {
      *(float4*)&Ash[row * 40 + seg * 8] = a0;
    }
    if constexpr (BF32) {
      float x[8] = {b0.x, b0.y, b0.z, b0.w, b1.x, b1.y, b1.z, b1.w};
      bfrag h;
#pragma unroll
      for (int j = 0; j < 8; j++) h[j] = (__bf16)x[j];
      *(bfrag*)&Bsh[row * 40 + seg * 8] = h;
    } else {
      *(float4*)&Bsh[row * 40 + seg * 8] = b0;
      if constexpr (LO) *(float4*)&Bsl[row * 40 + seg * 8] = bl0;
    }
    __syncthreads();

    bfrag ah[2], al[2], bh[2], bl[2];
#pragma unroll
    for (int mi = 0; mi < 2; mi++) {
      ah[mi] = *(bfrag*)&Ash[(wm + mi * 16 + ln) * 40 + qd * 8];
      if constexpr (LO) al[mi] = *(bfrag*)&Asl[(wm + mi * 16 + ln) * 40 + qd * 8];
    }
#pragma unroll
    for (int ni = 0; ni < 2; ni++) {
      bh[ni] = *(bfrag*)&Bsh[(wn + ni * 16 + ln) * 40 + qd * 8];
      if constexpr (LO) bl[ni] = *(bfrag*)&Bsl[(wn + ni * 16 + ln) * 40 + qd * 8];
    }
#pragma unroll
    for (int mi = 0; mi < 2; mi++)
#pragma unroll
      for (int ni = 0; ni < 2; ni++) {
        acc[mi][ni] = MFMA16(ah[mi], bh[ni], acc[mi][ni]);
        if constexpr (LO) {
          acc[mi][ni] = MFMA16(ah[mi], bl[ni], acc[mi][ni]);
          acc[mi][ni] = MFMA16(al[mi], bh[ni], acc[mi][ni]);
        }
      }
  }

#pragma unroll
  for (int mi = 0; mi < 2; mi++)
#pragma unroll
    for (int ni = 0; ni < 2; ni++)
#pragma unroll
      for (int r = 0; r < 4; r++) {
        const int mrow = m0 + wm + mi * 16 + qd * 4 + r;
        const int ncol = n0 + wn + ni * 16 + ln;
        const float c = acc[mi][ni][r];
        if constexpr (MODE == 0) {
          Cf[(size_t)mrow * 512 + ncol] = c;
        } else if constexpr (MODE == 1) {
          const int b = mrow >> 11, s = mrow & (S_ - 1);
          const int h = ncol >> 6, dk = ncol & 63;
          const size_t o = (((size_t)b * H_ + h) * S_ + s) * DK_ + dk;
          __bf16 hh = (__bf16)c;
          Oh[o] = hh;
          Ol[o] = (__bf16)(c - (float)hh);
        } else {  // MODE 2: V^T
          const int h = mrow >> 6, dk = mrow & 63;
          const int b = ncol >> 11, s = ncol & (S_ - 1);
          Oh[(((size_t)b * H_ + h) * DK_ + dk) * S_ + s] = (__bf16)c;
        }
      }
}

// ---------------------------------------------------------------------------
// Fused flash attention — R4 base + 32-kv-half online softmax to cut the
// register footprint (R6 post-mortem: occupancy is register-capped; R4's
// 120-reg kernel gets 2 waves/SIMD, >=136 gets 1; target <=170 total for 3).
// Per 64-kv tile: two sequential halves, each {QK 12 MFMA32 into ONE f16v z,
// mask FMA, online max + alpha, cacc rescale, exp->Ps half, PV k-slice}.
// This is the standard online-softmax algorithm with tile=32; Ps half-0 is
// stored relative to m-after-half-0, so MT moves to 32-granularity (64/row)
// and mean_rescale indexes tk2=(k0>>5)+(seg>>2). Straight-line (no branch).
// exp2 domain kept (Q carries SCALE/ln2); fp8 E kept; no skip-rescale.
// ---------------------------------------------------------------------------
__global__ __launch_bounds__(256, 3) void attn_fctx(
    const __bf16* __restrict__ Qh_, const __bf16* __restrict__ Ql_,
    const __bf16* __restrict__ Kh_, const __bf16* __restrict__ Kl_,
    const __bf16* __restrict__ VT, const float* __restrict__ mask,
    __bf16* __restrict__ CTXb, float* __restrict__ MR, float* __restrict__ LR,
    unsigned char* __restrict__ E, float* __restrict__ MT) {
  __shared__ __bf16 Ksh[64 * KSTR];
  __shared__ __bf16 Ksl[64 * KSTR];
  __shared__ __bf16 Vs[64 * KSTR];
  __shared__ __bf16 Ps[128 * PSTR];
  __shared__ float als[128];
  const int tid = threadIdx.x, lane = tid & 63, wv = tid >> 6;
  const int l31 = lane & 31, kh = lane >> 5;
  const int qd = lane >> 4, ln = lane & 15;
  const int bh = blockIdx.y;
  const int q0b = blockIdx.x * 128;
  const int q0w = q0b + wv * 32;
  const int srow = tid >> 2, sseg = tid & 3;

  // Q fragments (B-operand, 32x32x16): n = q = l31, k = ks*16 + kh*8 + j
  bfrag qhf[4], qlf[4];
#pragma unroll
  for (int ks = 0; ks < 4; ks++) {
    const size_t qb = ((size_t)bh * S_ + q0w + l31) * DK_ + ks * 16 + kh * 8;
    qhf[ks] = *(const bfrag*)&Qh_[qb];
    qlf[ks] = *(const bfrag*)&Ql_[qb];
  }

  float m = -3.0e38f, l = 0.f;   // per lane: q = q0w + l31 (dup across halves)
  f4 cacc[2][4];                  // [mt][nt] — PV 16-shape accumulators
#pragma unroll
  for (int mt = 0; mt < 2; mt++)
#pragma unroll
    for (int nt = 0; nt < 4; nt++)
#pragma unroll
      for (int r = 0; r < 4; r++) cacc[mt][nt][r] = 0.f;

  // prefetch tile 0
  float4 h0, h1, l0, l1, v0, v1;
  {
    const size_t kb = ((size_t)bh * S_ + srow) * DK_ + sseg * 16;
    const size_t vb = ((size_t)bh * DK_ + srow) * S_ + sseg * 16;
    h0 = *(const float4*)&Kh_[kb]; h1 = *(const float4*)&Kh_[kb + 8];
    l0 = *(const float4*)&Kl_[kb]; l1 = *(const float4*)&Kl_[kb + 8];
    v0 = *(const float4*)&VT[vb];  v1 = *(const float4*)&VT[vb + 8];
  }

  for (int kt = 0; kt < S_; kt += 64) {
    __syncthreads();
    *(float4*)&Ksh[srow * KSTR + sseg * 16] = h0;
    *(float4*)&Ksh[srow * KSTR + sseg * 16 + 8] = h1;
    *(float4*)&Ksl[srow * KSTR + sseg * 16] = l0;
    *(float4*)&Ksl[srow * KSTR + sseg * 16 + 8] = l1;
    *(float4*)&Vs[srow * KSTR + sseg * 16] = v0;
    *(float4*)&Vs[srow * KSTR + sseg * 16 + 8] = v1;
    __syncthreads();

    // prefetch next tile
    if (kt + 64 < S_) {
      const size_t kb = ((size_t)bh * S_ + kt + 64 + srow) * DK_ + sseg * 16;
      const size_t vb = ((size_t)bh * DK_ + srow) * S_ + kt + 64 + sseg * 16;
      h0 = *(const float4*)&Kh_[kb]; h1 = *(const float4*)&Kh_[kb + 8];
      l0 = *(const float4*)&Kl_[kb]; l1 = *(const float4*)&Kl_[kb + 8];
      v0 = *(const float4*)&VT[vb];  v1 = *(const float4*)&VT[vb + 8];
    }

    // ---- two 32-kv halves, online softmax per half ----
#pragma unroll
    for (int t = 0; t < 2; t++) {
      // mask for this half: entry (q = q0w+l31, kv = kt + t*32 + g*8 + 4*kh + i)
      f4 mk[4];
#pragma unroll
      for (int g = 0; g < 4; g++)
        mk[g] = *(const f4*)&mask[(size_t)(q0w + l31) * S_ + kt + t * 32 + g * 8 + 4 * kh];

      // z^T = K·Q^T for this half: 8 b128 reads, 12 MFMA32, 32 q
      f16v z;
#pragma unroll
      for (int r = 0; r < 16; r++) z[r] = 0.f;
#pragma unroll
      for (int ks = 0; ks < 4; ks++) {
        bfrag kbh = *(bfrag*)&Ksh[(t * 32 + l31) * KSTR + ks * 16 + kh * 8];
        bfrag kbl = *(bfrag*)&Ksl[(t * 32 + l31) * KSTR + ks * 16 + kh * 8];
        z = MFMA32(kbh, qhf[ks], z);
        z = MFMA32(kbl, qhf[ks], z);
        z = MFMA32(kbh, qlf[ks], z);
      }

      // add mask in log2 domain (z already carries SCALE/ln2 via Q)
#pragma unroll
      for (int r = 0; r < 16; r++)
        z[r] = fmaf(mk[r >> 2][r & 3], INVLN2, z[r]);

      // online max for this half
      float tm = z[0];
#pragma unroll
      for (int r = 1; r < 16; r++) tm = fmaxf(tm, z[r]);
      tm = fmaxf(tm, __shfl_xor(tm, 32, 64));
      const float nm = fmaxf(m, tm);
      const float al = exp2f(m - nm);
      m = nm;
      if (lane < 32) als[wv * 32 + lane] = al;

      // exp -> Ps half + row-sum
      float ls = 0.f;
#pragma unroll
      for (int g = 0; g < 4; g++) {
        const float e0 = exp2f(z[g * 4 + 0] - nm);
        const float e1 = exp2f(z[g * 4 + 1] - nm);
        const float e2 = exp2f(z[g * 4 + 2] - nm);
        const float e3 = exp2f(z[g * 4 + 3] - nm);
        ls += (e0 + e1) + (e2 + e3);
        b4 pk;
        pk[0] = (__bf16)e0; pk[1] = (__bf16)e1;
        pk[2] = (__bf16)e2; pk[3] = (__bf16)e3;
        *(b4*)&Ps[(wv * 32 + l31) * PSTR + t * 32 + g * 8 + 4 * kh] = pk;
      }
      l = l * al + ls;

      // per-half running max for mean_rescale (32-granularity)
      if (lane < 32)
        MT[((size_t)bh * 64 + (kt >> 5) + t) * S_ + q0w + lane] = m;

      // rescale cacc (row q = mt*16 + qd*4 + r)
#pragma unroll
      for (int mt = 0; mt < 2; mt++) {
        f4 av = *(f4*)&als[wv * 32 + mt * 16 + qd * 4];
#pragma unroll
        for (int nt = 0; nt < 4; nt++)
#pragma unroll
          for (int r = 0; r < 4; r++) cacc[mt][nt][r] *= av[r];
      }

      // PV k-slice for this half (8 MFMA16)
      bfrag pa[2];
#pragma unroll
      for (int mt = 0; mt < 2; mt++)
        pa[mt] = *(bfrag*)&Ps[(wv * 32 + mt * 16 + ln) * PSTR + t * 32 + qd * 8];
#pragma unroll
      for (int nt = 0; nt < 4; nt++) {
        bfrag vbf = *(bfrag*)&Vs[(nt * 16 + ln) * KSTR + t * 32 + qd * 8];
#pragma unroll
        for (int mt = 0; mt < 2; mt++)
          cacc[mt][nt] = MFMA16(pa[mt], vbf, cacc[mt][nt]);
      }
    }

    // ---- E copy: Ps rows -> global fp8 e4m3 (vectorized, coalesced) ----
#pragma unroll
    for (int c = 0; c < 4; c++) {
      const int row = wv * 32 + (lane >> 3) + c * 8;
      const int ch = lane & 7;
      bfrag pv = *(bfrag*)&Ps[row * PSTR + ch * 8];
      int lo = 0, hi = 0;
      lo = __builtin_amdgcn_cvt_pk_fp8_f32((float)pv[0], (float)pv[1], lo, 0);
      lo = __builtin_amdgcn_cvt_pk_fp8_f32((float)pv[2], (float)pv[3], lo, 1);
      hi = __builtin_amdgcn_cvt_pk_fp8_f32((float)pv[4], (float)pv[5], hi, 0);
      hi = __builtin_amdgcn_cvt_pk_fp8_f32((float)pv[6], (float)pv[7], hi, 1);
      u2 ev;
      ev.x = (unsigned int)lo;
      ev.y = (unsigned int)hi;
      __builtin_nontemporal_store(
          ev, (u2*)&E[((size_t)bh * S_ + q0b + row) * S_ + kt + ch * 8]);
    }
  }

  // ---- epilogue ----
  l += __shfl_xor(l, 32, 64);
  if (lane < 32) {
    MR[(size_t)bh * S_ + q0w + lane] = m;
    LR[(size_t)bh * S_ + q0w + lane] = l;
    als[wv * 32 + lane] = 1.0f / l;
  }
  const int b = bh >> 3, h = bh & 7;
#pragma unroll
  for (int mt = 0; mt < 2; mt++) {
    f4 iv = *(f4*)&als[wv * 32 + mt * 16 + qd * 4];
#pragma unroll
    for (int nt = 0; nt < 4; nt++)
#pragma unroll
      for (int r = 0; r < 4; r++)
        CTXb[((size_t)b * S_ + q0w + mt * 16 + qd * 4 + r) * D_ + h * DK_ + nt * 16 + ln] =
            (__bf16)(cacc[mt][nt][r] * iv[r]);
  }
}

// ---------------------------------------------------------------------------
// mean = (1/8) sum_h E * exp2(MT - m_fin) / l_fin  — bandwidth kernel.
// E fp8 e4m3; MT is per-32-kv-half running max in log2 domain:
// tk2 = (k0>>5) + (seg>>2) selects the half this thread's 8 k's belong to.
// ---------------------------------------------------------------------------
__global__ __launch_bounds__(256) void mean_rescale(
    const unsigned char* __restrict__ E, const float* __restrict__ MT,
    const float* __restrict__ MR, const float* __restrict__ LR,
    float* __restrict__ meanout) {
  const int t = threadIdx.x;
  const int qr = t >> 3, seg = t & 7;
  const int b = blockIdx.y, ks = blockIdx.z;
  const int qg = blockIdx.x * 32 + qr;

  float mf[H_], il[H_];
#pragma unroll
  for (int h = 0; h < H_; h++) {
    const int bh = b * H_ + h;
    mf[h] = MR[(size_t)bh * S_ + qg];
    il[h] = 1.0f / LR[(size_t)bh * S_ + qg];
  }

  for (int kc = 0; kc < 8; kc++) {
    const int k0 = ks * 512 + kc * 64;
    const int tk2 = (k0 >> 5) + (seg >> 2);
    float acc[8];
#pragma unroll
    for (int j = 0; j < 8; j++) acc[j] = 0.f;
#pragma unroll
    for (int h = 0; h < H_; h++) {
      const int bh = b * H_ + h;
      const float mt = MT[((size_t)bh * 64 + tk2) * S_ + qg];
      const float sc = exp2f(mt - mf[h]) * il[h];
      u2 e = __builtin_nontemporal_load(
          (const u2*)&E[((size_t)bh * S_ + qg) * S_ + k0 + seg * 8]);
      f2 p01 = __builtin_amdgcn_cvt_pk_f32_fp8((int)e.x, 0);
      f2 p23 = __builtin_amdgcn_cvt_pk_f32_fp8((int)e.x, 1);
      f2 p45 = __builtin_amdgcn_cvt_pk_f32_fp8((int)e.y, 0);
      f2 p67 = __builtin_amdgcn_cvt_pk_f32_fp8((int)e.y, 1);
      acc[0] += p01.x * sc; acc[1] += p01.y * sc;
      acc[2] += p23.x * sc; acc[3] += p23.y * sc;
      acc[4] += p45.x * sc; acc[5] += p45.y * sc;
      acc[6] += p67.x * sc; acc[7] += p67.y * sc;
    }
    f4 o0, o1;
    o0[0] = acc[0] * 0.125f; o0[1] = acc[1] * 0.125f;
    o0[2] = acc[2] * 0.125f; o0[3] = acc[3] * 0.125f;
    o1[0] = acc[4] * 0.125f; o1[1] = acc[5] * 0.125f;
    o1[2] = acc[6] * 0.125f; o1[3] = acc[7] * 0.125f;
    float* mp = &meanout[((size_t)b * S_ + qg) * S_ + k0 + seg * 8];
    *(f4*)&mp[0] = o0;
    *(f4*)&mp[4] = o1;
  }
}

// ---------------------------------------------------------------------------
extern "C" void kernel_launch(void* const* d_in, const int* in_sizes, int n_in,
                              void* d_out, int out_size, void* d_ws, size_t ws_size,
                              hipStream_t stream) {
  (void)in_sizes; (void)n_in; (void)out_size; (void)ws_size;
  const float* Zq = (const float*)d_in[0];
  const float* Zkv = (const float*)d_in[1];
  const float* mask = (const float*)d_in[2];
  const float* Wqkv = (const float*)d_in[3];
  const float* Wout = (const float*)d_in[4];

  float* out = (float*)d_out;                // [B,S,D]
  float* mean = out + (size_t)B_ * S_ * D_;  // [B,S,S]

  char* w = (char*)d_ws;
  const size_t WSZ = 512 * 512 * sizeof(__bf16);
  const size_t QSZ = (size_t)B_ * H_ * S_ * DK_ * sizeof(__bf16);
  __bf16* WqTh = (__bf16*)w; w += WSZ;
  __bf16* WqTl = (__bf16*)w; w += WSZ;
  __bf16* WkTh = (__bf16*)w; w += WSZ;
  __bf16* WkTl = (__bf16*)w; w += WSZ;
  __bf16* WvTh = (__bf16*)w; w += WSZ;
  __bf16* WoTh = (__bf16*)w; w += WSZ;
  __bf16* Qh = (__bf16*)w; w += QSZ;
  __bf16* Ql = (__bf16*)w; w += QSZ;
  __bf16* Kh = (__bf16*)w; w += QSZ;
  __bf16* Kl = (__bf16*)w; w += QSZ;
  __bf16* VTh = (__bf16*)w; w += QSZ;
  __bf16* CTXb = (__bf16*)w; w += QSZ;
  float* MR = (float*)w; w += (size_t)B_ * H_ * S_ * sizeof(float);
  float* LR = (float*)w; w += (size_t)B_ * H_ * S_ * sizeof(float);
  float* MT = (float*)w; w += (size_t)B_ * H_ * 64 * S_ * sizeof(float);       // 16.8 MB
  unsigned char* E = (unsigned char*)w; w += (size_t)B_ * H_ * S_ * S_;        // 134 MB (fp8)

  wtr_all<<<dim3(1024, 4), 256, 0, stream>>>(Wqkv, Wout, WqTh, WqTl, WkTh, WkTl, WvTh, WoTh);

  qk_proj<<<dim3(8, 128, 2), 256, 0, stream>>>(
      Zq, Zkv, WqTh, WqTl, WkTh, WkTl, Qh, Ql, Kh, Kl);
  gemm_mfma<false, true, false, 2><<<dim3(128, 8), 256, 0, stream>>>(
      WvTh, Zkv, nullptr, nullptr, VTh, nullptr);

  attn_fctx<<<dim3(16, 32), 256, 0, stream>>>(Qh, Ql, Kh, Kl, VTh, mask, CTXb, MR, LR, E, MT);
  mean_rescale<<<dim3(64, 4, 4), 256, 0, stream>>>(E, MT, MR, LR, mean);

  gemm_mfma<false, false, false, 0><<<dim3(8, 128), 256, 0, stream>>>(
      CTXb, WoTh, nullptr, out, nullptr, nullptr);
}

// Round 8
// 383.772 us; speedup vs baseline: 1.2951x; 1.2951x over previous
//
#include <hip/hip_runtime.h>
#include <cstdint>
#include <math.h>

#define B_ 4
#define S_ 2048
#define D_ 512
#define H_ 8
#define DK_ 64
#define SCALE 0.125f
#define INVLN2 1.4426950408889634f
#define QSCALE (SCALE * INVLN2)   // folded into Q at projection time
#define KSTR 84   // K/V LDS row stride in bf16 (measured conflict-free)
#define PSTR 68   // Ps LDS row stride in bf16 (measured conflict-free)

using bfrag = __attribute__((ext_vector_type(8))) __bf16;
using b4    = __attribute__((ext_vector_type(4))) __bf16;
using f4    = __attribute__((ext_vector_type(4))) float;
using f2    = __attribute__((ext_vector_type(2))) float;
using f16v  = __attribute__((ext_vector_type(16))) float;
using u2    = __attribute__((ext_vector_type(2))) unsigned int;
using u4    = __attribute__((ext_vector_type(4))) unsigned int;

#define MFMA16(a, b, c) __builtin_amdgcn_mfma_f32_16x16x32_bf16(a, b, c, 0, 0, 0)
#define MFMA32(a, b, c) __builtin_amdgcn_mfma_f32_32x32x16_bf16(a, b, c, 0, 0, 0)

// ---------------------------------------------------------------------------
// All 4 weight transposes in one launch: grid (1024, 4).
// ---------------------------------------------------------------------------
__global__ __launch_bounds__(256) void wtr_all(
    const float* __restrict__ Wqkv, const float* __restrict__ Wout,
    __bf16* __restrict__ WqTh, __bf16* __restrict__ WqTl,
    __bf16* __restrict__ WkTh, __bf16* __restrict__ WkTl,
    __bf16* __restrict__ WvTh, __bf16* __restrict__ WoTh) {
  const int by = blockIdx.y;
  const int idx = blockIdx.x * 256 + threadIdx.x;  // 512*512
  const int k = idx & 511, n = idx >> 9;
  const float* W = (by == 3) ? Wout : Wqkv;
  const int ldw = (by == 3) ? 512 : 1536;
  const int c0 = (by == 3) ? 0 : by * 512;
  const float x = W[(size_t)k * ldw + c0 + n];
  const __bf16 h = (__bf16)x;
  __bf16* th = (by == 0) ? WqTh : (by == 1) ? WkTh : (by == 2) ? WvTh : WoTh;
  th[(size_t)n * 512 + k] = h;
  if (by < 2) {
    __bf16* tl = (by == 0) ? WqTl : WkTl;
    tl[(size_t)n * 512 + k] = (__bf16)(x - (float)h);
  }
}

// ---------------------------------------------------------------------------
// Merged Q+K projection: grid (8, 128, 2); z=0 -> Q (scaled by SCALE/ln2 for
// the exp2-domain softmax), z=1 -> K. Verified passing in 3 prior rounds.
// ---------------------------------------------------------------------------
__global__ __launch_bounds__(256) void qk_proj(
    const float* __restrict__ Zq, const float* __restrict__ Zkv,
    const __bf16* __restrict__ WqTh, const __bf16* __restrict__ WqTl,
    const __bf16* __restrict__ WkTh, const __bf16* __restrict__ WkTl,
    __bf16* __restrict__ Qh, __bf16* __restrict__ Ql,
    __bf16* __restrict__ Kh, __bf16* __restrict__ Kl) {
  __shared__ __bf16 Ash[64 * 40];
  __shared__ __bf16 Asl[64 * 40];
  __shared__ __bf16 Bsh[64 * 40];
  __shared__ __bf16 Bsl[64 * 40];

  const int zz = blockIdx.z;
  const float* A = zz ? Zkv : Zq;
  const __bf16* Bhp = zz ? WkTh : WqTh;
  const __bf16* Blp = zz ? WkTl : WqTl;
  __bf16* Oh = zz ? Kh : Qh;
  __bf16* Ol = zz ? Kl : Ql;
  const float cs = zz ? 1.0f : QSCALE;

  const int tid = threadIdx.x;
  const int m0 = blockIdx.y * 64, n0 = blockIdx.x * 64;
  const int row = tid >> 2, seg = tid & 3;
  const int lane = tid & 63, wv = tid >> 6;
  const int wm = (wv & 1) * 32, wn = (wv >> 1) * 32;
  const int qd = lane >> 4, ln = lane & 15;

  f4 acc[2][2];
#pragma unroll
  for (int i = 0; i < 2; i++)
#pragma unroll
    for (int j = 0; j < 2; j++)
#pragma unroll
      for (int r = 0; r < 4; r++) acc[i][j][r] = 0.f;

  for (int kt = 0; kt < 512; kt += 32) {
    const size_t abase = (size_t)(m0 + row) * 512 + kt + seg * 8;
    const size_t bbase = (size_t)(n0 + row) * 512 + kt + seg * 8;
    float4 a0 = *(const float4*)&A[abase];
    float4 a1 = *(const float4*)&A[abase + 4];
    float4 b0 = *(const float4*)&Bhp[bbase];
    float4 bl0 = *(const float4*)&Blp[bbase];
    __syncthreads();
    {
      float x[8] = {a0.x, a0.y, a0.z, a0.w, a1.x, a1.y, a1.z, a1.w};
      bfrag h, l;
#pragma unroll
      for (int j = 0; j < 8; j++) {
        h[j] = (__bf16)x[j];
        l[j] = (__bf16)(x[j] - (float)h[j]);
      }
      *(bfrag*)&Ash[row * 40 + seg * 8] = h;
      *(bfrag*)&Asl[row * 40 + seg * 8] = l;
    }
    *(float4*)&Bsh[row * 40 + seg * 8] = b0;
    *(float4*)&Bsl[row * 40 + seg * 8] = bl0;
    __syncthreads();

    bfrag ah[2], al[2], bh[2], bl[2];
#pragma unroll
    for (int mi = 0; mi < 2; mi++) {
      ah[mi] = *(bfrag*)&Ash[(wm + mi * 16 + ln) * 40 + qd * 8];
      al[mi] = *(bfrag*)&Asl[(wm + mi * 16 + ln) * 40 + qd * 8];
    }
#pragma unroll
    for (int ni = 0; ni < 2; ni++) {
      bh[ni] = *(bfrag*)&Bsh[(wn + ni * 16 + ln) * 40 + qd * 8];
      bl[ni] = *(bfrag*)&Bsl[(wn + ni * 16 + ln) * 40 + qd * 8];
    }
#pragma unroll
    for (int mi = 0; mi < 2; mi++)
#pragma unroll
      for (int ni = 0; ni < 2; ni++) {
        acc[mi][ni] = MFMA16(ah[mi], bh[ni], acc[mi][ni]);
        acc[mi][ni] = MFMA16(ah[mi], bl[ni], acc[mi][ni]);
        acc[mi][ni] = MFMA16(al[mi], bh[ni], acc[mi][ni]);
      }
  }

#pragma unroll
  for (int mi = 0; mi < 2; mi++)
#pragma unroll
    for (int ni = 0; ni < 2; ni++)
#pragma unroll
      for (int r = 0; r < 4; r++) {
        const int mrow = m0 + wm + mi * 16 + qd * 4 + r;
        const int ncol = n0 + wn + ni * 16 + ln;
        const float c = acc[mi][ni][r] * cs;
        const int b = mrow >> 11, s = mrow & (S_ - 1);
        const int h = ncol >> 6, dk = ncol & 63;
        const size_t o = (((size_t)b * H_ + h) * S_ + s) * DK_ + dk;
        __bf16 hh = (__bf16)c;
        Oh[o] = hh;
        Ol[o] = (__bf16)(c - (float)hh);
      }
}

// ---------------------------------------------------------------------------
// Split-bf16 MFMA GEMM (template kept for V^T MODE2 and out MODE0).
// ---------------------------------------------------------------------------
template <bool AF32, bool BF32, bool LO, int MODE>
__global__ __launch_bounds__(256) void gemm_mfma(
    const void* __restrict__ Ap, const void* __restrict__ Bp, const void* __restrict__ Blop,
    float* __restrict__ Cf, __bf16* __restrict__ Oh, __bf16* __restrict__ Ol) {
  __shared__ __bf16 Ash[64 * 40];
  __shared__ __bf16 Asl[64 * 40];
  __shared__ __bf16 Bsh[64 * 40];
  __shared__ __bf16 Bsl[64 * 40];

  const int tid = threadIdx.x;
  const int m0 = blockIdx.y * 64, n0 = blockIdx.x * 64;
  const int row = tid >> 2, seg = tid & 3;
  const int lane = tid & 63, wv = tid >> 6;
  const int wm = (wv & 1) * 32, wn = (wv >> 1) * 32;
  const int qd = lane >> 4, ln = lane & 15;

  f4 acc[2][2];
#pragma unroll
  for (int i = 0; i < 2; i++)
#pragma unroll
    for (int j = 0; j < 2; j++)
#pragma unroll
      for (int r = 0; r < 4; r++) acc[i][j][r] = 0.f;

  for (int kt = 0; kt < 512; kt += 32) {
    const size_t abase = (size_t)(m0 + row) * 512 + kt + seg * 8;
    const size_t bbase = (size_t)(n0 + row) * 512 + kt + seg * 8;
    float4 a0, a1, b0, b1, bl0;
    if constexpr (AF32) {
      const float* A = (const float*)Ap;
      a0 = *(const float4*)&A[abase];
      a1 = *(const float4*)&A[abase + 4];
    } else {
      const __bf16* A = (const __bf16*)Ap;
      a0 = *(const float4*)&A[abase];
    }
    if constexpr (BF32) {
      const float* Bm = (const float*)Bp;
      b0 = *(const float4*)&Bm[bbase];
      b1 = *(const float4*)&Bm[bbase + 4];
    } else {
      const __bf16* Bm = (const __bf16*)Bp;
      b0 = *(const float4*)&Bm[bbase];
      if constexpr (LO) {
        const __bf16* Bl = (const __bf16*)Blop;
        bl0 = *(const float4*)&Bl[bbase];
      }
    }
    __syncthreads();
    if constexpr (AF32) {
      float x[8] = {a0.x, a0.y, a0.z, a0.w, a1.x, a1.y, a1.z, a1.w};
      bfrag h, l;
#pragma unroll
      for (int j = 0; j < 8; j++) {
        h[j] = (__bf16)x[j];
        l[j] = (__bf16)(x[j] - (float)h[j]);
      }
      *(bfrag*)&Ash[row * 40 + seg * 8] = h;
      if constexpr (LO) *(bfrag*)&Asl[row * 40 + seg * 8] = l;
    } else {
      *(float4*)&Ash[row * 40 + seg * 8] = a0;
    }
    if constexpr (BF32) {
      float x[8] = {b0.x, b0.y, b0.z, b0.w, b1.x, b1.y, b1.z, b1.w};
      bfrag h;
#pragma unroll
      for (int j = 0; j < 8; j++) h[j] = (__bf16)x[j];
      *(bfrag*)&Bsh[row * 40 + seg * 8] = h;
    } else {
      *(float4*)&Bsh[row * 40 + seg * 8] = b0;
      if constexpr (LO) *(float4*)&Bsl[row * 40 + seg * 8] = bl0;
    }
    __syncthreads();

    bfrag ah[2], al[2], bh[2], bl[2];
#pragma unroll
    for (int mi = 0; mi < 2; mi++) {
      ah[mi] = *(bfrag*)&Ash[(wm + mi * 16 + ln) * 40 + qd * 8];
      if constexpr (LO) al[mi] = *(bfrag*)&Asl[(wm + mi * 16 + ln) * 40 + qd * 8];
    }
#pragma unroll
    for (int ni = 0; ni < 2; ni++) {
      bh[ni] = *(bfrag*)&Bsh[(wn + ni * 16 + ln) * 40 + qd * 8];
      if constexpr (LO) bl[ni] = *(bfrag*)&Bsl[(wn + ni * 16 + ln) * 40 + qd * 8];
    }
#pragma unroll
    for (int mi = 0; mi < 2; mi++)
#pragma unroll
      for (int ni = 0; ni < 2; ni++) {
        acc[mi][ni] = MFMA16(ah[mi], bh[ni], acc[mi][ni]);
        if constexpr (LO) {
          acc[mi][ni] = MFMA16(ah[mi], bl[ni], acc[mi][ni]);
          acc[mi][ni] = MFMA16(al[mi], bh[ni], acc[mi][ni]);
        }
      }
  }

#pragma unroll
  for (int mi = 0; mi < 2; mi++)
#pragma unroll
    for (int ni = 0; ni < 2; ni++)
#pragma unroll
      for (int r = 0; r < 4; r++) {
        const int mrow = m0 + wm + mi * 16 + qd * 4 + r;
        const int ncol = n0 + wn + ni * 16 + ln;
        const float c = acc[mi][ni][r];
        if constexpr (MODE == 0) {
          Cf[(size_t)mrow * 512 + ncol] = c;
        } else if constexpr (MODE == 1) {
          const int b = mrow >> 11, s = mrow & (S_ - 1);
          const int h = ncol >> 6, dk = ncol & 63;
          const size_t o = (((size_t)b * H_ + h) * S_ + s) * DK_ + dk;
          __bf16 hh = (__bf16)c;
          Oh[o] = hh;
          Ol[o] = (__bf16)(c - (float)hh);
        } else {  // MODE 2: V^T
          const int h = mrow >> 6, dk = mrow & 63;
          const int b = ncol >> 11, s = ncol & (S_ - 1);
          Oh[(((size_t)b * H_ + h) * DK_ + dk) * S_ + s] = (__bf16)c;
        }
      }
}

// ---------------------------------------------------------------------------
// Fused flash attention — EXACT R4 body (best measured: 139.4 µs, VGPR 120)
// with only the exp2-domain substitution: Q carries SCALE/ln2 (from qk_proj),
// mask added via FMA with INVLN2 (same inst count as R4's SCALE FMA), and
// exp2f instead of __expf (drops 32 v_mul/tile/lane). No other changes —
// R5/R6/R7 showed every structural edit of this body regresses.
// MR/MT hold log2-domain maxima (consumed as differences only).
// ---------------------------------------------------------------------------
__global__ __launch_bounds__(256) void attn_fctx(
    const __bf16* __restrict__ Qh_, const __bf16* __restrict__ Ql_,
    const __bf16* __restrict__ Kh_, const __bf16* __restrict__ Kl_,
    const __bf16* __restrict__ VT, const float* __restrict__ mask,
    __bf16* __restrict__ CTXb, float* __restrict__ MR, float* __restrict__ LR,
    unsigned char* __restrict__ E, float* __restrict__ MT) {
  __shared__ __bf16 Ksh[64 * KSTR];
  __shared__ __bf16 Ksl[64 * KSTR];
  __shared__ __bf16 Vs[64 * KSTR];
  __shared__ __bf16 Ps[128 * PSTR];
  __shared__ float als[128];
  const int tid = threadIdx.x, lane = tid & 63, wv = tid >> 6;
  const int l31 = lane & 31, kh = lane >> 5;
  const int qd = lane >> 4, ln = lane & 15;
  const int bh = blockIdx.y;
  const int q0b = blockIdx.x * 128;
  const int q0w = q0b + wv * 32;
  const int srow = tid >> 2, sseg = tid & 3;

  // Q fragments (B-operand, 32x32x16): n = q = l31, k = ks*16 + kh*8 + j
  bfrag qhf[4], qlf[4];
#pragma unroll
  for (int ks = 0; ks < 4; ks++) {
    const size_t qb = ((size_t)bh * S_ + q0w + l31) * DK_ + ks * 16 + kh * 8;
    qhf[ks] = *(const bfrag*)&Qh_[qb];
    qlf[ks] = *(const bfrag*)&Ql_[qb];
  }

  float m = -3.0e38f, l = 0.f;   // per lane: q = q0w + l31 (dup across halves)
  f4 cacc[2][4];                  // [mt][nt] — PV 16-shape accumulators
#pragma unroll
  for (int mt = 0; mt < 2; mt++)
#pragma unroll
    for (int nt = 0; nt < 4; nt++)
#pragma unroll
      for (int r = 0; r < 4; r++) cacc[mt][nt][r] = 0.f;

  // prefetch tile 0
  float4 h0, h1, l0, l1, v0, v1;
  {
    const size_t kb = ((size_t)bh * S_ + srow) * DK_ + sseg * 16;
    const size_t vb = ((size_t)bh * DK_ + srow) * S_ + sseg * 16;
    h0 = *(const float4*)&Kh_[kb]; h1 = *(const float4*)&Kh_[kb + 8];
    l0 = *(const float4*)&Kl_[kb]; l1 = *(const float4*)&Kl_[kb + 8];
    v0 = *(const float4*)&VT[vb];  v1 = *(const float4*)&VT[vb + 8];
  }

  for (int kt = 0; kt < S_; kt += 64) {
    __syncthreads();
    *(float4*)&Ksh[srow * KSTR + sseg * 16] = h0;
    *(float4*)&Ksh[srow * KSTR + sseg * 16 + 8] = h1;
    *(float4*)&Ksl[srow * KSTR + sseg * 16] = l0;
    *(float4*)&Ksl[srow * KSTR + sseg * 16 + 8] = l1;
    *(float4*)&Vs[srow * KSTR + sseg * 16] = v0;
    *(float4*)&Vs[srow * KSTR + sseg * 16 + 8] = v1;
    __syncthreads();

    // mask, transposed order: entry (q = q0w+l31, kv = kt + t*32 + g*8 + 4*kh + i)
    f4 mk[2][4];
#pragma unroll
    for (int t = 0; t < 2; t++)
#pragma unroll
      for (int g = 0; g < 4; g++)
        mk[t][g] = *(const f4*)&mask[(size_t)(q0w + l31) * S_ + kt + t * 32 + g * 8 + 4 * kh];

    // prefetch next tile
    if (kt + 64 < S_) {
      const size_t kb = ((size_t)bh * S_ + kt + 64 + srow) * DK_ + sseg * 16;
      const size_t vb = ((size_t)bh * DK_ + srow) * S_ + kt + 64 + sseg * 16;
      h0 = *(const float4*)&Kh_[kb]; h1 = *(const float4*)&Kh_[kb + 8];
      l0 = *(const float4*)&Kl_[kb]; l1 = *(const float4*)&Kl_[kb + 8];
      v0 = *(const float4*)&VT[vb];  v1 = *(const float4*)&VT[vb + 8];
    }

    // ---- z^T = K·Q^T, 32x32x16 split-3: 16 b128 reads, 24 MFMAs, 32 q ----
    f16v z[2];
#pragma unroll
    for (int t = 0; t < 2; t++)
#pragma unroll
      for (int r = 0; r < 16; r++) z[t][r] = 0.f;
#pragma unroll
    for (int t = 0; t < 2; t++)
#pragma unroll
      for (int ks = 0; ks < 4; ks++) {
        bfrag kbh = *(bfrag*)&Ksh[(t * 32 + l31) * KSTR + ks * 16 + kh * 8];
        bfrag kbl = *(bfrag*)&Ksl[(t * 32 + l31) * KSTR + ks * 16 + kh * 8];
        z[t] = MFMA32(kbh, qhf[ks], z[t]);
        z[t] = MFMA32(kbl, qhf[ks], z[t]);
        z[t] = MFMA32(kbh, qlf[ks], z[t]);
      }

    // ---- add mask in log2 domain: y = z + mk/ln2 (z carries SCALE/ln2) ----
#pragma unroll
    for (int t = 0; t < 2; t++)
#pragma unroll
      for (int r = 0; r < 16; r++)
        z[t][r] = fmaf(mk[t][r >> 2][r & 3], INVLN2, z[t][r]);

    // ---- online softmax (base-2): per-lane q column, 1 cross-lane reduce ----
    float tm = z[0][0];
#pragma unroll
    for (int t = 0; t < 2; t++)
#pragma unroll
      for (int r = 0; r < 16; r++) tm = fmaxf(tm, z[t][r]);
    tm = fmaxf(tm, __shfl_xor(tm, 32, 64));
    const float nm = fmaxf(m, tm);
    const float al = exp2f(m - nm);
    m = nm;
    if (lane < 32) als[wv * 32 + lane] = al;

    float ls = 0.f;
#pragma unroll
    for (int t = 0; t < 2; t++)
#pragma unroll
      for (int g = 0; g < 4; g++) {
        const float e0 = exp2f(z[t][g * 4 + 0] - nm);
        const float e1 = exp2f(z[t][g * 4 + 1] - nm);
        const float e2 = exp2f(z[t][g * 4 + 2] - nm);
        const float e3 = exp2f(z[t][g * 4 + 3] - nm);
        ls += (e0 + e1) + (e2 + e3);
        b4 pk;
        pk[0] = (__bf16)e0; pk[1] = (__bf16)e1;
        pk[2] = (__bf16)e2; pk[3] = (__bf16)e3;
        *(b4*)&Ps[(wv * 32 + l31) * PSTR + t * 32 + g * 8 + 4 * kh] = pk;
      }
    l = l * al + ls;

    if (lane < 32)
      MT[((size_t)bh * 32 + (kt >> 6)) * S_ + q0w + lane] = m;

    // ---- rescale cacc with alpha from LDS (row q = mt*16 + qd*4 + r) ----
#pragma unroll
    for (int mt = 0; mt < 2; mt++) {
      f4 av = *(f4*)&als[wv * 32 + mt * 16 + qd * 4];
#pragma unroll
      for (int nt = 0; nt < 4; nt++)
#pragma unroll
        for (int r = 0; r < 4; r++) cacc[mt][nt][r] *= av[r];
    }

    // ---- PV (16 MFMA, 16-shape): P m=q (2 tiles), V n=d (4 tiles), k=kv ----
    bfrag pa[2][2];
#pragma unroll
    for (int mt = 0; mt < 2; mt++)
#pragma unroll
      for (int ks = 0; ks < 2; ks++)
        pa[mt][ks] = *(bfrag*)&Ps[(wv * 32 + mt * 16 + ln) * PSTR + ks * 32 + qd * 8];
#pragma unroll
    for (int nt = 0; nt < 4; nt++)
#pragma unroll
      for (int ks = 0; ks < 2; ks++) {
        bfrag vbf = *(bfrag*)&Vs[(nt * 16 + ln) * KSTR + ks * 32 + qd * 8];
#pragma unroll
        for (int mt = 0; mt < 2; mt++)
          cacc[mt][nt] = MFMA16(pa[mt][ks], vbf, cacc[mt][nt]);
      }

    // ---- E copy: Ps rows -> global fp8 e4m3 (vectorized, coalesced) ----
#pragma unroll
    for (int c = 0; c < 4; c++) {
      const int row = wv * 32 + (lane >> 3) + c * 8;
      const int ch = lane & 7;
      bfrag pv = *(bfrag*)&Ps[row * PSTR + ch * 8];
      int lo = 0, hi = 0;
      lo = __builtin_amdgcn_cvt_pk_fp8_f32((float)pv[0], (float)pv[1], lo, 0);
      lo = __builtin_amdgcn_cvt_pk_fp8_f32((float)pv[2], (float)pv[3], lo, 1);
      hi = __builtin_amdgcn_cvt_pk_fp8_f32((float)pv[4], (float)pv[5], hi, 0);
      hi = __builtin_amdgcn_cvt_pk_fp8_f32((float)pv[6], (float)pv[7], hi, 1);
      u2 ev;
      ev.x = (unsigned int)lo;
      ev.y = (unsigned int)hi;
      __builtin_nontemporal_store(
          ev, (u2*)&E[((size_t)bh * S_ + q0b + row) * S_ + kt + ch * 8]);
    }
  }

  // ---- epilogue ----
  l += __shfl_xor(l, 32, 64);
  if (lane < 32) {
    MR[(size_t)bh * S_ + q0w + lane] = m;
    LR[(size_t)bh * S_ + q0w + lane] = l;
    als[wv * 32 + lane] = 1.0f / l;
  }
  const int b = bh >> 3, h = bh & 7;
#pragma unroll
  for (int mt = 0; mt < 2; mt++) {
    f4 iv = *(f4*)&als[wv * 32 + mt * 16 + qd * 4];
#pragma unroll
    for (int nt = 0; nt < 4; nt++)
#pragma unroll
      for (int r = 0; r < 4; r++)
        CTXb[((size_t)b * S_ + q0w + mt * 16 + qd * 4 + r) * D_ + h * DK_ + nt * 16 + ln] =
            (__bf16)(cacc[mt][nt][r] * iv[r]);
  }
}

// ---------------------------------------------------------------------------
// mean = (1/8) sum_h E * exp2(MT - m_fin) / l_fin  — bandwidth kernel.
// RELAID OUT for coalescing: block = 8 q x 32 k-segments; each lane loads
// 16 B of E -> 512 B contiguous per wave per head (old layout: 64 B chunks).
// Writes 16 f32/lane -> 2 KB contiguous per wave. Grid (S/8, B, S/512).
// E fp8 e4m3; MT/MR log2-domain (differences only).
// ---------------------------------------------------------------------------
__global__ __launch_bounds__(256) void mean_rescale(
    const unsigned char* __restrict__ E, const float* __restrict__ MT,
    const float* __restrict__ MR, const float* __restrict__ LR,
    float* __restrict__ meanout) {
  const int t = threadIdx.x;
  const int qr = t >> 5, sk = t & 31;
  const int b = blockIdx.y;
  const int qg = blockIdx.x * 8 + qr;
  const int k0 = blockIdx.z * 512 + sk * 16;
  const int tk = k0 >> 6;

  float acc[16];
#pragma unroll
  for (int j = 0; j < 16; j++) acc[j] = 0.f;

#pragma unroll
  for (int h = 0; h < H_; h++) {
    const int bh = b * H_ + h;
    const float mf = MR[(size_t)bh * S_ + qg];
    const float il = 1.0f / LR[(size_t)bh * S_ + qg];
    const float mt = MT[((size_t)bh * 32 + tk) * S_ + qg];
    const float sc = exp2f(mt - mf) * il;
    u4 e = __builtin_nontemporal_load(
        (const u4*)&E[((size_t)bh * S_ + qg) * S_ + k0]);
#pragma unroll
    for (int wd = 0; wd < 4; wd++) {
      f2 plo = __builtin_amdgcn_cvt_pk_f32_fp8((int)e[wd], 0);
      f2 phi = __builtin_amdgcn_cvt_pk_f32_fp8((int)e[wd], 1);
      acc[wd * 4 + 0] += plo.x * sc;
      acc[wd * 4 + 1] += plo.y * sc;
      acc[wd * 4 + 2] += phi.x * sc;
      acc[wd * 4 + 3] += phi.y * sc;
    }
  }

  float* mp = &meanout[((size_t)b * S_ + qg) * S_ + k0];
#pragma unroll
  for (int wd = 0; wd < 4; wd++) {
    f4 o;
    o[0] = acc[wd * 4 + 0] * 0.125f;
    o[1] = acc[wd * 4 + 1] * 0.125f;
    o[2] = acc[wd * 4 + 2] * 0.125f;
    o[3] = acc[wd * 4 + 3] * 0.125f;
    *(f4*)&mp[wd * 4] = o;
  }
}

// ---------------------------------------------------------------------------
extern "C" void kernel_launch(void* const* d_in, const int* in_sizes, int n_in,
                              void* d_out, int out_size, void* d_ws, size_t ws_size,
                              hipStream_t stream) {
  (void)in_sizes; (void)n_in; (void)out_size; (void)ws_size;
  const float* Zq = (const float*)d_in[0];
  const float* Zkv = (const float*)d_in[1];
  const float* mask = (const float*)d_in[2];
  const float* Wqkv = (const float*)d_in[3];
  const float* Wout = (const float*)d_in[4];

  float* out = (float*)d_out;                // [B,S,D]
  float* mean = out + (size_t)B_ * S_ * D_;  // [B,S,S]

  char* w = (char*)d_ws;
  const size_t WSZ = 512 * 512 * sizeof(__bf16);
  const size_t QSZ = (size_t)B_ * H_ * S_ * DK_ * sizeof(__bf16);
  __bf16* WqTh = (__bf16*)w; w += WSZ;
  __bf16* WqTl = (__bf16*)w; w += WSZ;
  __bf16* WkTh = (__bf16*)w; w += WSZ;
  __bf16* WkTl = (__bf16*)w; w += WSZ;
  __bf16* WvTh = (__bf16*)w; w += WSZ;
  __bf16* WoTh = (__bf16*)w; w += WSZ;
  __bf16* Qh = (__bf16*)w; w += QSZ;
  __bf16* Ql = (__bf16*)w; w += QSZ;
  __bf16* Kh = (__bf16*)w; w += QSZ;
  __bf16* Kl = (__bf16*)w; w += QSZ;
  __bf16* VTh = (__bf16*)w; w += QSZ;
  __bf16* CTXb = (__bf16*)w; w += QSZ;
  float* MR = (float*)w; w += (size_t)B_ * H_ * S_ * sizeof(float);
  float* LR = (float*)w; w += (size_t)B_ * H_ * S_ * sizeof(float);
  float* MT = (float*)w; w += (size_t)B_ * H_ * 32 * S_ * sizeof(float);       // 8.4 MB
  unsigned char* E = (unsigned char*)w; w += (size_t)B_ * H_ * S_ * S_;        // 134 MB (fp8)

  wtr_all<<<dim3(1024, 4), 256, 0, stream>>>(Wqkv, Wout, WqTh, WqTl, WkTh, WkTl, WvTh, WoTh);

  qk_proj<<<dim3(8, 128, 2), 256, 0, stream>>>(
      Zq, Zkv, WqTh, WqTl, WkTh, WkTl, Qh, Ql, Kh, Kl);
  gemm_mfma<false, true, false, 2><<<dim3(128, 8), 256, 0, stream>>>(
      WvTh, Zkv, nullptr, nullptr, VTh, nullptr);

  attn_fctx<<<dim3(16, 32), 256, 0, stream>>>(Qh, Ql, Kh, Kl, VTh, mask, CTXb, MR, LR, E, MT);
  mean_rescale<<<dim3(256, 4, 4), 256, 0, stream>>>(E, MT, MR, LR, mean);

  gemm_mfma<false, false, false, 0><<<dim3(8, 128), 256, 0, stream>>>(
      CTXb, WoTh, nullptr, out, nullptr, nullptr);
}

// Round 10
// 371.417 us; speedup vs baseline: 1.3382x; 1.0333x over previous
//
#include <hip/hip_runtime.h>
#include <cstdint>
#include <math.h>

#define B_ 4
#define S_ 2048
#define D_ 512
#define H_ 8
#define DK_ 64
#define SCALE 0.125f
#define KSTR 84   // K/V LDS row stride in bf16 (measured conflict-free)
#define PSTR 68   // Ps LDS row stride in bf16 (measured conflict-free)

using bfrag = __attribute__((ext_vector_type(8))) __bf16;
using b4    = __attribute__((ext_vector_type(4))) __bf16;
using f4    = __attribute__((ext_vector_type(4))) float;
using f2    = __attribute__((ext_vector_type(2))) float;
using f16v  = __attribute__((ext_vector_type(16))) float;
using u2    = __attribute__((ext_vector_type(2))) unsigned int;
using u4    = __attribute__((ext_vector_type(4))) unsigned int;

#define MFMA16(a, b, c) __builtin_amdgcn_mfma_f32_16x16x32_bf16(a, b, c, 0, 0, 0)
#define MFMA32(a, b, c) __builtin_amdgcn_mfma_f32_32x32x16_bf16(a, b, c, 0, 0, 0)

// ---------------------------------------------------------------------------
// All 4 weight transposes in one launch: grid (1024, 4).
// ---------------------------------------------------------------------------
__global__ __launch_bounds__(256) void wtr_all(
    const float* __restrict__ Wqkv, const float* __restrict__ Wout,
    __bf16* __restrict__ WqTh, __bf16* __restrict__ WqTl,
    __bf16* __restrict__ WkTh, __bf16* __restrict__ WkTl,
    __bf16* __restrict__ WvTh, __bf16* __restrict__ WoTh) {
  const int by = blockIdx.y;
  const int idx = blockIdx.x * 256 + threadIdx.x;  // 512*512
  const int k = idx & 511, n = idx >> 9;
  const float* W = (by == 3) ? Wout : Wqkv;
  const int ldw = (by == 3) ? 512 : 1536;
  const int c0 = (by == 3) ? 0 : by * 512;
  const float x = W[(size_t)k * ldw + c0 + n];
  const __bf16 h = (__bf16)x;
  __bf16* th = (by == 0) ? WqTh : (by == 1) ? WkTh : (by == 2) ? WvTh : WoTh;
  th[(size_t)n * 512 + k] = h;
  if (by < 2) {
    __bf16* tl = (by == 0) ? WqTl : WkTl;
    tl[(size_t)n * 512 + k] = (__bf16)(x - (float)h);
  }
}

// ---------------------------------------------------------------------------
// Merged Q+K projection: grid (8, 128, 2); z=0 -> Q, z=1 -> K.
// (No Q pre-scale: R8 showed exp2-domain regresses; SCALE applied in attn.)
// ---------------------------------------------------------------------------
__global__ __launch_bounds__(256) void qk_proj(
    const float* __restrict__ Zq, const float* __restrict__ Zkv,
    const __bf16* __restrict__ WqTh, const __bf16* __restrict__ WqTl,
    const __bf16* __restrict__ WkTh, const __bf16* __restrict__ WkTl,
    __bf16* __restrict__ Qh, __bf16* __restrict__ Ql,
    __bf16* __restrict__ Kh, __bf16* __restrict__ Kl) {
  __shared__ __bf16 Ash[64 * 40];
  __shared__ __bf16 Asl[64 * 40];
  __shared__ __bf16 Bsh[64 * 40];
  __shared__ __bf16 Bsl[64 * 40];

  const int zz = blockIdx.z;
  const float* A = zz ? Zkv : Zq;
  const __bf16* Bhp = zz ? WkTh : WqTh;
  const __bf16* Blp = zz ? WkTl : WqTl;
  __bf16* Oh = zz ? Kh : Qh;
  __bf16* Ol = zz ? Kl : Ql;

  const int tid = threadIdx.x;
  const int m0 = blockIdx.y * 64, n0 = blockIdx.x * 64;
  const int row = tid >> 2, seg = tid & 3;
  const int lane = tid & 63, wv = tid >> 6;
  const int wm = (wv & 1) * 32, wn = (wv >> 1) * 32;
  const int qd = lane >> 4, ln = lane & 15;

  f4 acc[2][2];
#pragma unroll
  for (int i = 0; i < 2; i++)
#pragma unroll
    for (int j = 0; j < 2; j++)
#pragma unroll
      for (int r = 0; r < 4; r++) acc[i][j][r] = 0.f;

  for (int kt = 0; kt < 512; kt += 32) {
    const size_t abase = (size_t)(m0 + row) * 512 + kt + seg * 8;
    const size_t bbase = (size_t)(n0 + row) * 512 + kt + seg * 8;
    float4 a0 = *(const float4*)&A[abase];
    float4 a1 = *(const float4*)&A[abase + 4];
    float4 b0 = *(const float4*)&Bhp[bbase];
    float4 bl0 = *(const float4*)&Blp[bbase];
    __syncthreads();
    {
      float x[8] = {a0.x, a0.y, a0.z, a0.w, a1.x, a1.y, a1.z, a1.w};
      bfrag h, l;
#pragma unroll
      for (int j = 0; j < 8; j++) {
        h[j] = (__bf16)x[j];
        l[j] = (__bf16)(x[j] - (float)h[j]);
      }
      *(bfrag*)&Ash[row * 40 + seg * 8] = h;
      *(bfrag*)&Asl[row * 40 + seg * 8] = l;
    }
    *(float4*)&Bsh[row * 40 + seg * 8] = b0;
    *(float4*)&Bsl[row * 40 + seg * 8] = bl0;
    __syncthreads();

    bfrag ah[2], al[2], bh[2], bl[2];
#pragma unroll
    for (int mi = 0; mi < 2; mi++) {
      ah[mi] = *(bfrag*)&Ash[(wm + mi * 16 + ln) * 40 + qd * 8];
      al[mi] = *(bfrag*)&Asl[(wm + mi * 16 + ln) * 40 + qd * 8];
    }
#pragma unroll
    for (int ni = 0; ni < 2; ni++) {
      bh[ni] = *(bfrag*)&Bsh[(wn + ni * 16 + ln) * 40 + qd * 8];
      bl[ni] = *(bfrag*)&Bsl[(wn + ni * 16 + ln) * 40 + qd * 8];
    }
#pragma unroll
    for (int mi = 0; mi < 2; mi++)
#pragma unroll
      for (int ni = 0; ni < 2; ni++) {
        acc[mi][ni] = MFMA16(ah[mi], bh[ni], acc[mi][ni]);
        acc[mi][ni] = MFMA16(ah[mi], bl[ni], acc[mi][ni]);
        acc[mi][ni] = MFMA16(al[mi], bh[ni], acc[mi][ni]);
      }
  }

#pragma unroll
  for (int mi = 0; mi < 2; mi++)
#pragma unroll
    for (int ni = 0; ni < 2; ni++)
#pragma unroll
      for (int r = 0; r < 4; r++) {
        const int mrow = m0 + wm + mi * 16 + qd * 4 + r;
        const int ncol = n0 + wn + ni * 16 + ln;
        const float c = acc[mi][ni][r];
        const int b = mrow >> 11, s = mrow & (S_ - 1);
        const int h = ncol >> 6, dk = ncol & 63;
        const size_t o = (((size_t)b * H_ + h) * S_ + s) * DK_ + dk;
        __bf16 hh = (__bf16)c;
        Oh[o] = hh;
        Ol[o] = (__bf16)(c - (float)hh);
      }
}

// ---------------------------------------------------------------------------
// Split-bf16 MFMA GEMM (template kept for V^T MODE2 and out MODE0).
// ---------------------------------------------------------------------------
template <bool AF32, bool BF32, bool LO, int MODE>
__global__ __launch_bounds__(256) void gemm_mfma(
    const void* __restrict__ Ap, const void* __restrict__ Bp, const void* __restrict__ Blop,
    float* __restrict__ Cf, __bf16* __restrict__ Oh, __bf16* __restrict__ Ol) {
  __shared__ __bf16 Ash[64 * 40];
  __shared__ __bf16 Asl[64 * 40];
  __shared__ __bf16 Bsh[64 * 40];
  __shared__ __bf16 Bsl[64 * 40];

  const int tid = threadIdx.x;
  const int m0 = blockIdx.y * 64, n0 = blockIdx.x * 64;
  const int row = tid >> 2, seg = tid & 3;
  const int lane = tid & 63, wv = tid >> 6;
  const int wm = (wv & 1) * 32, wn = (wv >> 1) * 32;
  const int qd = lane >> 4, ln = lane & 15;

  f4 acc[2][2];
#pragma unroll
  for (int i = 0; i < 2; i++)
#pragma unroll
    for (int j = 0; j < 2; j++)
#pragma unroll
      for (int r = 0; r < 4; r++) acc[i][j][r] = 0.f;

  for (int kt = 0; kt < 512; kt += 32) {
    const size_t abase = (size_t)(m0 + row) * 512 + kt + seg * 8;
    const size_t bbase = (size_t)(n0 + row) * 512 + kt + seg * 8;
    float4 a0, a1, b0, b1, bl0;
    if constexpr (AF32) {
      const float* A = (const float*)Ap;
      a0 = *(const float4*)&A[abase];
      a1 = *(const float4*)&A[abase + 4];
    } else {
      const __bf16* A = (const __bf16*)Ap;
      a0 = *(const float4*)&A[abase];
    }
    if constexpr (BF32) {
      const float* Bm = (const float*)Bp;
      b0 = *(const float4*)&Bm[bbase];
      b1 = *(const float4*)&Bm[bbase + 4];
    } else {
      const __bf16* Bm = (const __bf16*)Bp;
      b0 = *(const float4*)&Bm[bbase];
      if constexpr (LO) {
        const __bf16* Bl = (const __bf16*)Blop;
        bl0 = *(const float4*)&Bl[bbase];
      }
    }
    __syncthreads();
    if constexpr (AF32) {
      float x[8] = {a0.x, a0.y, a0.z, a0.w, a1.x, a1.y, a1.z, a1.w};
      bfrag h, l;
#pragma unroll
      for (int j = 0; j < 8; j++) {
        h[j] = (__bf16)x[j];
        l[j] = (__bf16)(x[j] - (float)h[j]);
      }
      *(bfrag*)&Ash[row * 40 + seg * 8] = h;
      if constexpr (LO) *(bfrag*)&Asl[row * 40 + seg * 8] = l;
    } else {
      *(float4*)&Ash[row * 40 + seg * 8] = a0;
    }
    if constexpr (BF32) {
      float x[8] = {b0.x, b0.y, b0.z, b0.w, b1.x, b1.y, b1.z, b1.w};
      bfrag h;
#pragma unroll
      for (int j = 0; j < 8; j++) h[j] = (__bf16)x[j];
      *(bfrag*)&Bsh[row * 40 + seg * 8] = h;
    } else {
      *(float4*)&Bsh[row * 40 + seg * 8] = b0;
      if constexpr (LO) *(float4*)&Bsl[row * 40 + seg * 8] = bl0;
    }
    __syncthreads();

    bfrag ah[2], al[2], bh[2], bl[2];
#pragma unroll
    for (int mi = 0; mi < 2; mi++) {
      ah[mi] = *(bfrag*)&Ash[(wm + mi * 16 + ln) * 40 + qd * 8];
      if constexpr (LO) al[mi] = *(bfrag*)&Asl[(wm + mi * 16 + ln) * 40 + qd * 8];
    }
#pragma unroll
    for (int ni = 0; ni < 2; ni++) {
      bh[ni] = *(bfrag*)&Bsh[(wn + ni * 16 + ln) * 40 + qd * 8];
      if constexpr (LO) bl[ni] = *(bfrag*)&Bsl[(wn + ni * 16 + ln) * 40 + qd * 8];
    }
#pragma unroll
    for (int mi = 0; mi < 2; mi++)
#pragma unroll
      for (int ni = 0; ni < 2; ni++) {
        acc[mi][ni] = MFMA16(ah[mi], bh[ni], acc[mi][ni]);
        if constexpr (LO) {
          acc[mi][ni] = MFMA16(ah[mi], bl[ni], acc[mi][ni]);
          acc[mi][ni] = MFMA16(al[mi], bh[ni], acc[mi][ni]);
        }
      }
  }

#pragma unroll
  for (int mi = 0; mi < 2; mi++)
#pragma unroll
    for (int ni = 0; ni < 2; ni++)
#pragma unroll
      for (int r = 0; r < 4; r++) {
        const int mrow = m0 + wm + mi * 16 + qd * 4 + r;
        const int ncol = n0 + wn + ni * 16 + ln;
        const float c = acc[mi][ni][r];
        if constexpr (MODE == 0) {
          Cf[(size_t)mrow * 512 + ncol] = c;
        } else if constexpr (MODE == 1) {
          const int b = mrow >> 11, s = mrow & (S_ - 1);
          const int h = ncol >> 6, dk = ncol & 63;
          const size_t o = (((size_t)b * H_ + h) * S_ + s) * DK_ + dk;
          __bf16 hh = (__bf16)c;
          Oh[o] = hh;
          Ol[o] = (__bf16)(c - (float)hh);
        } else {  // MODE 2: V^T
          const int h = mrow >> 6, dk = mrow & 63;
          const int b = ncol >> 11, s = ncol & (S_ - 1);
          Oh[(((size_t)b * H_ + h) * DK_ + dk) * S_ + s] = (__bf16)c;
        }
      }
}

// ---------------------------------------------------------------------------
// Fused flash attention — EXACT R4 body (best measured: 139.4 µs, VGPR 120).
// R8 post-mortem: exp2f is an OCML wrapper (VALUBusy 39->43, dur 139->164);
// __expf is the fast intrinsic. R5/R6/R7 showed every structural edit of
// this body regresses. This body is FROZEN: SCALE fmaf + __expf + fp8 E.
// ---------------------------------------------------------------------------
__global__ __launch_bounds__(256) void attn_fctx(
    const __bf16* __restrict__ Qh_, const __bf16* __restrict__ Ql_,
    const __bf16* __restrict__ Kh_, const __bf16* __restrict__ Kl_,
    const __bf16* __restrict__ VT, const float* __restrict__ mask,
    __bf16* __restrict__ CTXb, float* __restrict__ MR, float* __restrict__ LR,
    unsigned char* __restrict__ E, float* __restrict__ MT) {
  __shared__ __bf16 Ksh[64 * KSTR];
  __shared__ __bf16 Ksl[64 * KSTR];
  __shared__ __bf16 Vs[64 * KSTR];
  __shared__ __bf16 Ps[128 * PSTR];
  __shared__ float als[128];
  const int tid = threadIdx.x, lane = tid & 63, wv = tid >> 6;
  const int l31 = lane & 31, kh = lane >> 5;
  const int qd = lane >> 4, ln = lane & 15;
  const int bh = blockIdx.y;
  const int q0b = blockIdx.x * 128;
  const int q0w = q0b + wv * 32;
  const int srow = tid >> 2, sseg = tid & 3;

  // Q fragments (B-operand, 32x32x16): n = q = l31, k = ks*16 + kh*8 + j
  bfrag qhf[4], qlf[4];
#pragma unroll
  for (int ks = 0; ks < 4; ks++) {
    const size_t qb = ((size_t)bh * S_ + q0w + l31) * DK_ + ks * 16 + kh * 8;
    qhf[ks] = *(const bfrag*)&Qh_[qb];
    qlf[ks] = *(const bfrag*)&Ql_[qb];
  }

  float m = -3.0e38f, l = 0.f;   // per lane: q = q0w + l31 (dup across halves)
  f4 cacc[2][4];                  // [mt][nt] — PV 16-shape accumulators
#pragma unroll
  for (int mt = 0; mt < 2; mt++)
#pragma unroll
    for (int nt = 0; nt < 4; nt++)
#pragma unroll
      for (int r = 0; r < 4; r++) cacc[mt][nt][r] = 0.f;

  // prefetch tile 0
  float4 h0, h1, l0, l1, v0, v1;
  {
    const size_t kb = ((size_t)bh * S_ + srow) * DK_ + sseg * 16;
    const size_t vb = ((size_t)bh * DK_ + srow) * S_ + sseg * 16;
    h0 = *(const float4*)&Kh_[kb]; h1 = *(const float4*)&Kh_[kb + 8];
    l0 = *(const float4*)&Kl_[kb]; l1 = *(const float4*)&Kl_[kb + 8];
    v0 = *(const float4*)&VT[vb];  v1 = *(const float4*)&VT[vb + 8];
  }

  for (int kt = 0; kt < S_; kt += 64) {
    __syncthreads();
    *(float4*)&Ksh[srow * KSTR + sseg * 16] = h0;
    *(float4*)&Ksh[srow * KSTR + sseg * 16 + 8] = h1;
    *(float4*)&Ksl[srow * KSTR + sseg * 16] = l0;
    *(float4*)&Ksl[srow * KSTR + sseg * 16 + 8] = l1;
    *(float4*)&Vs[srow * KSTR + sseg * 16] = v0;
    *(float4*)&Vs[srow * KSTR + sseg * 16 + 8] = v1;
    __syncthreads();

    // mask, transposed order: entry (q = q0w+l31, kv = kt + t*32 + g*8 + 4*kh + i)
    f4 mk[2][4];
#pragma unroll
    for (int t = 0; t < 2; t++)
#pragma unroll
      for (int g = 0; g < 4; g++)
        mk[t][g] = *(const f4*)&mask[(size_t)(q0w + l31) * S_ + kt + t * 32 + g * 8 + 4 * kh];

    // prefetch next tile
    if (kt + 64 < S_) {
      const size_t kb = ((size_t)bh * S_ + kt + 64 + srow) * DK_ + sseg * 16;
      const size_t vb = ((size_t)bh * DK_ + srow) * S_ + kt + 64 + sseg * 16;
      h0 = *(const float4*)&Kh_[kb]; h1 = *(const float4*)&Kh_[kb + 8];
      l0 = *(const float4*)&Kl_[kb]; l1 = *(const float4*)&Kl_[kb + 8];
      v0 = *(const float4*)&VT[vb];  v1 = *(const float4*)&VT[vb + 8];
    }

    // ---- z^T = K·Q^T, 32x32x16 split-3: 16 b128 reads, 24 MFMAs, 32 q ----
    f16v z[2];
#pragma unroll
    for (int t = 0; t < 2; t++)
#pragma unroll
      for (int r = 0; r < 16; r++) z[t][r] = 0.f;
#pragma unroll
    for (int t = 0; t < 2; t++)
#pragma unroll
      for (int ks = 0; ks < 4; ks++) {
        bfrag kbh = *(bfrag*)&Ksh[(t * 32 + l31) * KSTR + ks * 16 + kh * 8];
        bfrag kbl = *(bfrag*)&Ksl[(t * 32 + l31) * KSTR + ks * 16 + kh * 8];
        z[t] = MFMA32(kbh, qhf[ks], z[t]);
        z[t] = MFMA32(kbl, qhf[ks], z[t]);
        z[t] = MFMA32(kbh, qlf[ks], z[t]);
      }

    // ---- scale + mask in place ----
#pragma unroll
    for (int t = 0; t < 2; t++)
#pragma unroll
      for (int r = 0; r < 16; r++)
        z[t][r] = fmaf(z[t][r], SCALE, mk[t][r >> 2][r & 3]);

    // ---- online softmax: per-lane q column, 1 cross-lane reduce ----
    float tm = z[0][0];
#pragma unroll
    for (int t = 0; t < 2; t++)
#pragma unroll
      for (int r = 0; r < 16; r++) tm = fmaxf(tm, z[t][r]);
    tm = fmaxf(tm, __shfl_xor(tm, 32, 64));
    const float nm = fmaxf(m, tm);
    const float al = __expf(m - nm);
    m = nm;
    if (lane < 32) als[wv * 32 + lane] = al;

    float ls = 0.f;
#pragma unroll
    for (int t = 0; t < 2; t++)
#pragma unroll
      for (int g = 0; g < 4; g++) {
        const float e0 = __expf(z[t][g * 4 + 0] - nm);
        const float e1 = __expf(z[t][g * 4 + 1] - nm);
        const float e2 = __expf(z[t][g * 4 + 2] - nm);
        const float e3 = __expf(z[t][g * 4 + 3] - nm);
        ls += (e0 + e1) + (e2 + e3);
        b4 pk;
        pk[0] = (__bf16)e0; pk[1] = (__bf16)e1;
        pk[2] = (__bf16)e2; pk[3] = (__bf16)e3;
        *(b4*)&Ps[(wv * 32 + l31) * PSTR + t * 32 + g * 8 + 4 * kh] = pk;
      }
    l = l * al + ls;

    if (lane < 32)
      MT[((size_t)bh * 32 + (kt >> 6)) * S_ + q0w + lane] = m;

    // ---- rescale cacc with alpha from LDS (row q = mt*16 + qd*4 + r) ----
#pragma unroll
    for (int mt = 0; mt < 2; mt++) {
      f4 av = *(f4*)&als[wv * 32 + mt * 16 + qd * 4];
#pragma unroll
      for (int nt = 0; nt < 4; nt++)
#pragma unroll
        for (int r = 0; r < 4; r++) cacc[mt][nt][r] *= av[r];
    }

    // ---- PV (16 MFMA, 16-shape): P m=q (2 tiles), V n=d (4 tiles), k=kv ----
    bfrag pa[2][2];
#pragma unroll
    for (int mt = 0; mt < 2; mt++)
#pragma unroll
      for (int ks = 0; ks < 2; ks++)
        pa[mt][ks] = *(bfrag*)&Ps[(wv * 32 + mt * 16 + ln) * PSTR + ks * 32 + qd * 8];
#pragma unroll
    for (int nt = 0; nt < 4; nt++)
#pragma unroll
      for (int ks = 0; ks < 2; ks++) {
        bfrag vbf = *(bfrag*)&Vs[(nt * 16 + ln) * KSTR + ks * 32 + qd * 8];
#pragma unroll
        for (int mt = 0; mt < 2; mt++)
          cacc[mt][nt] = MFMA16(pa[mt][ks], vbf, cacc[mt][nt]);
      }

    // ---- E copy: Ps rows -> global fp8 e4m3 (vectorized, coalesced) ----
#pragma unroll
    for (int c = 0; c < 4; c++) {
      const int row = wv * 32 + (lane >> 3) + c * 8;
      const int ch = lane & 7;
      bfrag pv = *(bfrag*)&Ps[row * PSTR + ch * 8];
      int lo = 0, hi = 0;
      lo = __builtin_amdgcn_cvt_pk_fp8_f32((float)pv[0], (float)pv[1], lo, 0);
      lo = __builtin_amdgcn_cvt_pk_fp8_f32((float)pv[2], (float)pv[3], lo, 1);
      hi = __builtin_amdgcn_cvt_pk_fp8_f32((float)pv[4], (float)pv[5], hi, 0);
      hi = __builtin_amdgcn_cvt_pk_fp8_f32((float)pv[6], (float)pv[7], hi, 1);
      u2 ev;
      ev.x = (unsigned int)lo;
      ev.y = (unsigned int)hi;
      __builtin_nontemporal_store(
          ev, (u2*)&E[((size_t)bh * S_ + q0b + row) * S_ + kt + ch * 8]);
    }
  }

  // ---- epilogue ----
  l += __shfl_xor(l, 32, 64);
  if (lane < 32) {
    MR[(size_t)bh * S_ + q0w + lane] = m;
    LR[(size_t)bh * S_ + q0w + lane] = l;
    als[wv * 32 + lane] = 1.0f / l;
  }
  const int b = bh >> 3, h = bh & 7;
#pragma unroll
  for (int mt = 0; mt < 2; mt++) {
    f4 iv = *(f4*)&als[wv * 32 + mt * 16 + qd * 4];
#pragma unroll
    for (int nt = 0; nt < 4; nt++)
#pragma unroll
      for (int r = 0; r < 4; r++)
        CTXb[((size_t)b * S_ + q0w + mt * 16 + qd * 4 + r) * D_ + h * DK_ + nt * 16 + ln] =
            (__bf16)(cacc[mt][nt][r] * iv[r]);
  }
}

// ---------------------------------------------------------------------------
// mean = (1/8) sum_h E * exp(MT - m_fin) / l_fin  — bandwidth kernel.
// R8's coalesced layout (verified, ~20 µs gain): block = 8 q x 32 k-segments;
// each lane loads 16 B of E -> 512 B contiguous per wave per head; writes
// 16 f32/lane -> 2 KB contiguous per wave. Grid (S/8, B, S/512).
// E fp8 e4m3; MT/MR natural-log domain (matches R4 attn).
// ---------------------------------------------------------------------------
__global__ __launch_bounds__(256) void mean_rescale(
    const unsigned char* __restrict__ E, const float* __restrict__ MT,
    const float* __restrict__ MR, const float* __restrict__ LR,
    float* __restrict__ meanout) {
  const int t = threadIdx.x;
  const int qr = t >> 5, sk = t & 31;
  const int b = blockIdx.y;
  const int qg = blockIdx.x * 8 + qr;
  const int k0 = blockIdx.z * 512 + sk * 16;
  const int tk = k0 >> 6;

  float acc[16];
#pragma unroll
  for (int j = 0; j < 16; j++) acc[j] = 0.f;

#pragma unroll
  for (int h = 0; h < H_; h++) {
    const int bh = b * H_ + h;
    const float mf = MR[(size_t)bh * S_ + qg];
    const float il = 1.0f / LR[(size_t)bh * S_ + qg];
    const float mt = MT[((size_t)bh * 32 + tk) * S_ + qg];
    const float sc = __expf(mt - mf) * il;
    u4 e = __builtin_nontemporal_load(
        (const u4*)&E[((size_t)bh * S_ + qg) * S_ + k0]);
#pragma unroll
    for (int wd = 0; wd < 4; wd++) {
      f2 plo = __builtin_amdgcn_cvt_pk_f32_fp8((int)e[wd], 0);
      f2 phi = __builtin_amdgcn_cvt_pk_f32_fp8((int)e[wd], 1);
      acc[wd * 4 + 0] += plo.x * sc;
      acc[wd * 4 + 1] += plo.y * sc;
      acc[wd * 4 + 2] += phi.x * sc;
      acc[wd * 4 + 3] += phi.y * sc;
    }
  }

  float* mp = &meanout[((size_t)b * S_ + qg) * S_ + k0];
#pragma unroll
  for (int wd = 0; wd < 4; wd++) {
    f4 o;
    o[0] = acc[wd * 4 + 0] * 0.125f;
    o[1] = acc[wd * 4 + 1] * 0.125f;
    o[2] = acc[wd * 4 + 2] * 0.125f;
    o[3] = acc[wd * 4 + 3] * 0.125f;
    *(f4*)&mp[wd * 4] = o;
  }
}

// ---------------------------------------------------------------------------
extern "C" void kernel_launch(void* const* d_in, const int* in_sizes, int n_in,
                              void* d_out, int out_size, void* d_ws, size_t ws_size,
                              hipStream_t stream) {
  (void)in_sizes; (void)n_in; (void)out_size; (void)ws_size;
  const float* Zq = (const float*)d_in[0];
  const float* Zkv = (const float*)d_in[1];
  const float* mask = (const float*)d_in[2];
  const float* Wqkv = (const float*)d_in[3];
  const float* Wout = (const float*)d_in[4];

  float* out = (float*)d_out;                // [B,S,D]
  float* mean = out + (size_t)B_ * S_ * D_;  // [B,S,S]

  char* w = (char*)d_ws;
  const size_t WSZ = 512 * 512 * sizeof(__bf16);
  const size_t QSZ = (size_t)B_ * H_ * S_ * DK_ * sizeof(__bf16);
  __bf16* WqTh = (__bf16*)w; w += WSZ;
  __bf16* WqTl = (__bf16*)w; w += WSZ;
  __bf16* WkTh = (__bf16*)w; w += WSZ;
  __bf16* WkTl = (__bf16*)w; w += WSZ;
  __bf16* WvTh = (__bf16*)w; w += WSZ;
  __bf16* WoTh = (__bf16*)w; w += WSZ;
  __bf16* Qh = (__bf16*)w; w += QSZ;
  __bf16* Ql = (__bf16*)w; w += QSZ;
  __bf16* Kh = (__bf16*)w; w += QSZ;
  __bf16* Kl = (__bf16*)w; w += QSZ;
  __bf16* VTh = (__bf16*)w; w += QSZ;
  __bf16* CTXb = (__bf16*)w; w += QSZ;
  float* MR = (float*)w; w += (size_t)B_ * H_ * S_ * sizeof(float);
  float* LR = (float*)w; w += (size_t)B_ * H_ * S_ * sizeof(float);
  float* MT = (float*)w; w += (size_t)B_ * H_ * 32 * S_ * sizeof(float);       // 8.4 MB
  unsigned char* E = (unsigned char*)w; w += (size_t)B_ * H_ * S_ * S_;        // 134 MB (fp8)

  wtr_all<<<dim3(1024, 4), 256, 0, stream>>>(Wqkv, Wout, WqTh, WqTl, WkTh, WkTl, WvTh, WoTh);

  qk_proj<<<dim3(8, 128, 2), 256, 0, stream>>>(
      Zq, Zkv, WqTh, WqTl, WkTh, WkTl, Qh, Ql, Kh, Kl);
  gemm_mfma<false, true, false, 2><<<dim3(128, 8), 256, 0, stream>>>(
      WvTh, Zkv, nullptr, nullptr, VTh, nullptr);

  attn_fctx<<<dim3(16, 32), 256, 0, stream>>>(Qh, Ql, Kh, Kl, VTh, mask, CTXb, MR, LR, E, MT);
  mean_rescale<<<dim3(256, 4, 4), 256, 0, stream>>>(E, MT, MR, LR, mean);

  gemm_mfma<false, false, false, 0><<<dim3(8, 128), 256, 0, stream>>>(
      CTXb, WoTh, nullptr, out, nullptr, nullptr);
}